// Round 5
// baseline (155.425 us; speedup 1.0000x reference)
//
#include <hip/hip_runtime.h>
#include <math.h>

#define NROWS 65536      // B*T
#define DIM   64
#define KCODE 1024
#define TAU_M 8e-3f      // packed-margin threshold (split err ~1e-3 + packing err <=2.4e-3)

typedef __attribute__((ext_vector_type(8))) short short8;
typedef __bf16 bf16_t;
typedef bf16_t bf16x8 __attribute__((ext_vector_type(8)));
typedef __attribute__((ext_vector_type(4))) float f32x4;

union B8 { bf16x8 v; short8 s; ushort u[8]; };

// ws layout (bytes):
//   [0      .. 262143]  ushort emb_frag  (1024 codes x 64 dims x {hi,lo}) in MFMA B order
//   [262144 .. 266239]  float  e2h[1024]  = -(||e||^2 - 64) / 2   (shifted: argmin-invariant)
//   [266240 .. 270335]  int    counts[1024]
//   [270336 .. 270339]  float  sse
//   [270352 .. 335887]  uchar  flags[NROWS]
#define WS_EMBF(ws)   ((ushort*)(ws))
#define WS_E2H(ws)    ((float*)((char*)(ws) + 262144))
#define WS_COUNTS(ws) ((int*)((char*)(ws) + 266240))
#define WS_SSE(ws)    ((float*)((char*)(ws) + 270336))
#define WS_FLAGS(ws)  ((unsigned char*)(ws) + 270352)

__device__ __forceinline__ ushort f2bf(float x) {
  unsigned u = __float_as_uint(x);
  u += 0x7FFFu + ((u >> 16) & 1u);           // RNE
  return (ushort)(u >> 16);
}
__device__ __forceinline__ float bf2f(ushort h) {
  return __uint_as_float(((unsigned)h) << 16);
}

__device__ __forceinline__ void gload16(const int4* g, int4* l) {
  __builtin_amdgcn_global_load_lds((const __attribute__((address_space(1))) void*)g,
                                   (__attribute__((address_space(3))) void*)l, 16, 0, 0);
}

// ---------------------------------------------------------------- init ----
// grid 64 blocks x 256 threads; block = one 16-code tile (4KB fragment image).
// Thread t: code c = t&15, dims (t>>4)*4 .. +3. Also e2h, counts, sse.
__global__ __launch_bounds__(256) void vq_init(const float* __restrict__ emb, void* ws) {
  __shared__ __align__(16) ushort timg[2048];   // 4KB tile image
  __shared__ float e2p[256];

  const int g = blockIdx.x, t = threadIdx.x;    // g = global tile (16 codes)
  const int cl = t & 15;                        // local code (= MFMA col)
  const int d0 = (t >> 4) * 4;                  // dim range start
  const int gc = g * 16 + cl;

  const float4 v = *(const float4*)(emb + (size_t)gc * DIM + d0);
  float xs[4] = {v.x, v.y, v.z, v.w};
  float acc = 0.f;
#pragma unroll
  for (int u = 0; u < 4; ++u) {
    int d = d0 + u;
    float x = xs[u];
    ushort hs = f2bf(x);
    ushort ls = f2bf(x - bf2f(hs));
    int ks = d >> 5, kq = (d >> 3) & 3, e = d & 7;
    int lane = cl + kq * 16;
    int off = ks * 1024 + lane * 8 + e;         // ushort units within tile image
    timg[off] = hs;
    timg[off + 512] = ls;
    acc += x * x;
  }
  e2p[t] = acc;
  __syncthreads();
  if (t < 16) {
    float s = 0.f;
#pragma unroll
    for (int j = 0; j < 16; ++j) s += e2p[t + 16 * j];
    WS_E2H(ws)[g * 16 + t] = -0.5f * (s - 64.0f);   // shifted offset
    WS_COUNTS(ws)[g * 16 + t] = 0;
  }
  if (g == 0 && t == 0) *WS_SSE(ws) = 0.f;
  __syncthreads();
  ((int4*)WS_EMBF(ws))[g * 256 + t] = ((const int4*)timg)[t];
}

// ---------------------------------------------------------------- main ----
// 1024 threads = 16 waves = 4 row-groups x 4 code-groups; block = 256 rows;
// grid = 256 (1 block/CU, 4 waves/SIMD). Code-group owns 4 strips (256 codes),
// double-buffered via global_load_lds.
// amdgpu_waves_per_eu(4,4): pin the register allocator to 4 waves/EU ->
// 128-VGPR budget (launch_bounds' 2nd arg only sets the MIN, and the backend's
// default 8-waves/EU target capped us at 64 VGPRs -> 150MB/dispatch of spills).
__global__ __launch_bounds__(1024)
__attribute__((amdgpu_waves_per_eu(4, 4)))
void vq_main(const float* __restrict__ z,
             const float* __restrict__ emb,
             void* ws,
             float* __restrict__ outp) {
  __shared__ __align__(16) int4 ebuf[4][2][1024];   // [cgroup][dbuf][16KB strip]
  __shared__ float e2s[KCODE];
  __shared__ int   win[256];
  __shared__ float ssew[16];

  const int tid  = threadIdx.x;
  const int lane = tid & 63, w = tid >> 6;
  const int rg = w & 3, cg = w >> 2;
  const int col = lane & 15, kq = lane >> 4;
  const int ct = tid & 255;                        // index within code-group
  const int rowbase = blockIdx.x * 256 + rg * 64;
  const int invLane = 1023 - col;

  const int4* ef4 = (const int4*)WS_EMBF(ws);

  // prologue stage: strip 0 of this cgroup -> ebuf[cg][0] (async DMA)
  {
    const int4* src = ef4 + (size_t)(cg * 4) * 1024 + ct;
    int4* dst = &ebuf[cg][0][ct];
#pragma unroll
    for (int k = 0; k < 4; ++k) gload16(src + k * 256, dst + k * 256);
  }
  // stage e2h -> LDS (4KB)
  if (tid < 256) ((float4*)e2s)[tid] = ((const float4*)WS_E2H(ws))[tid];

  // A fragments: 4 row-groups-of-16 x 2 ksteps, hi+lo, in registers all kernel
  B8 ah[4][2], al[4][2];
#pragma unroll
  for (int g = 0; g < 4; ++g) {
    int row = rowbase + g * 16 + col;
    const float* zr = z + (size_t)row * DIM;
#pragma unroll
    for (int ks = 0; ks < 2; ++ks) {
      const float4* p = (const float4*)(zr + ks * 32 + kq * 8);
      float4 x0 = p[0], x1 = p[1];
      float vv[8] = {x0.x, x0.y, x0.z, x0.w, x1.x, x1.y, x1.z, x1.w};
#pragma unroll
      for (int e = 0; e < 8; ++e) {
        ushort hs = f2bf(vv[e]);
        ah[g][ks].u[e] = hs;
        al[g][ks].u[e] = f2bf(vv[e] - bf2f(hs));
      }
    }
  }

  float b1[16], b2[16];         // packed top-2 of m = z.e - (e^2-64)/2 (index in low 10 bits)
#pragma unroll
  for (int q = 0; q < 16; ++q) { b1[q] = -3.4e38f; b2[q] = -3.4e38f; }

  for (int s = 0; s < 4; ++s) {
    __syncthreads();            // drains vmcnt: buf[s&1] ready; prev compute done
    if (s < 3) {                // T3 2-phase: issue next-strip DMA before compute
      const int4* src = ef4 + (size_t)(cg * 4 + s + 1) * 1024 + ct;
      int4* dst = &ebuf[cg][(s + 1) & 1][ct];
#pragma unroll
      for (int k = 0; k < 4; ++k) gload16(src + k * 256, dst + k * 256);
    }

    const short8* bp = (const short8*)&ebuf[cg][s & 1][0];
    const int sbase = (cg * 4 + s) * 64;
#pragma unroll
    for (int t = 0; t < 4; ++t) {
      float cinit = e2s[sbase + t * 16 + col];
      f32x4 cc = {cinit, cinit, cinit, cinit};
      int invc = invLane - (sbase + t * 16);

      B8 bh0, bl0;
      bh0.s = bp[(t * 4 + 0) * 64 + lane];
      bl0.s = bp[(t * 4 + 1) * 64 + lane];
      f32x4 a0 = __builtin_amdgcn_mfma_f32_16x16x32_bf16(ah[0][0].v, bh0.v, cc, 0, 0, 0);
      f32x4 a1 = __builtin_amdgcn_mfma_f32_16x16x32_bf16(ah[1][0].v, bh0.v, cc, 0, 0, 0);
      f32x4 a2 = __builtin_amdgcn_mfma_f32_16x16x32_bf16(ah[2][0].v, bh0.v, cc, 0, 0, 0);
      f32x4 a3 = __builtin_amdgcn_mfma_f32_16x16x32_bf16(ah[3][0].v, bh0.v, cc, 0, 0, 0);
      a0 = __builtin_amdgcn_mfma_f32_16x16x32_bf16(al[0][0].v, bh0.v, a0, 0, 0, 0);
      a1 = __builtin_amdgcn_mfma_f32_16x16x32_bf16(al[1][0].v, bh0.v, a1, 0, 0, 0);
      a2 = __builtin_amdgcn_mfma_f32_16x16x32_bf16(al[2][0].v, bh0.v, a2, 0, 0, 0);
      a3 = __builtin_amdgcn_mfma_f32_16x16x32_bf16(al[3][0].v, bh0.v, a3, 0, 0, 0);
      a0 = __builtin_amdgcn_mfma_f32_16x16x32_bf16(ah[0][0].v, bl0.v, a0, 0, 0, 0);
      a1 = __builtin_amdgcn_mfma_f32_16x16x32_bf16(ah[1][0].v, bl0.v, a1, 0, 0, 0);
      a2 = __builtin_amdgcn_mfma_f32_16x16x32_bf16(ah[2][0].v, bl0.v, a2, 0, 0, 0);
      a3 = __builtin_amdgcn_mfma_f32_16x16x32_bf16(ah[3][0].v, bl0.v, a3, 0, 0, 0);

      B8 bh1, bl1;
      bh1.s = bp[(t * 4 + 2) * 64 + lane];
      bl1.s = bp[(t * 4 + 3) * 64 + lane];
      a0 = __builtin_amdgcn_mfma_f32_16x16x32_bf16(ah[0][1].v, bh1.v, a0, 0, 0, 0);
      a1 = __builtin_amdgcn_mfma_f32_16x16x32_bf16(ah[1][1].v, bh1.v, a1, 0, 0, 0);
      a2 = __builtin_amdgcn_mfma_f32_16x16x32_bf16(ah[2][1].v, bh1.v, a2, 0, 0, 0);
      a3 = __builtin_amdgcn_mfma_f32_16x16x32_bf16(ah[3][1].v, bh1.v, a3, 0, 0, 0);
      a0 = __builtin_amdgcn_mfma_f32_16x16x32_bf16(al[0][1].v, bh1.v, a0, 0, 0, 0);
      a1 = __builtin_amdgcn_mfma_f32_16x16x32_bf16(al[1][1].v, bh1.v, a1, 0, 0, 0);
      a2 = __builtin_amdgcn_mfma_f32_16x16x32_bf16(al[2][1].v, bh1.v, a2, 0, 0, 0);
      a3 = __builtin_amdgcn_mfma_f32_16x16x32_bf16(al[3][1].v, bh1.v, a3, 0, 0, 0);
      a0 = __builtin_amdgcn_mfma_f32_16x16x32_bf16(ah[0][1].v, bl1.v, a0, 0, 0, 0);
      a1 = __builtin_amdgcn_mfma_f32_16x16x32_bf16(ah[1][1].v, bl1.v, a1, 0, 0, 0);
      a2 = __builtin_amdgcn_mfma_f32_16x16x32_bf16(ah[2][1].v, bl1.v, a2, 0, 0, 0);
      a3 = __builtin_amdgcn_mfma_f32_16x16x32_bf16(ah[3][1].v, bl1.v, a3, 0, 0, 0);

      f32x4 av[4] = {a0, a1, a2, a3};
#pragma unroll
      for (int g = 0; g < 4; ++g)
#pragma unroll
        for (int r = 0; r < 4; ++r) {
          int q = g * 4 + r;
          unsigned mb = (__float_as_uint(av[g][r]) & 0xFFFFFC00u) | (unsigned)invc;
          float mp = __uint_as_float(mb);
          float nb2 = __builtin_amdgcn_fmed3f(mp, b1[q], b2[q]);
          b1[q] = fmaxf(b1[q], mp);
          b2[q] = nb2;
        }
    }
  }

  __syncthreads();                       // all strip compute done; reuse ebuf as merge buf
  float2* redm = (float2*)&ebuf[0][0][0];  // [cg*4+quad][256 rows]
#pragma unroll
  for (int q = 0; q < 16; ++q) {
    float m1 = b1[q], m2 = b2[q];
#pragma unroll
    for (int off = 1; off <= 2; off <<= 1) {
      float om1 = __shfl_xor(m1, off, 64);
      float om2 = __shfl_xor(m2, off, 64);
      float mx2 = fmaxf(m2, om2);
      m2 = __builtin_amdgcn_fmed3f(m1, om1, mx2);
      m1 = fmaxf(m1, om1);
    }
    if ((col & 3) == 0) {
      int quad = col >> 2;
      int row = rg * 64 + (q >> 2) * 16 + kq * 4 + (q & 3);
      redm[(cg * 4 + quad) * 256 + row] = make_float2(m1, m2);
    }
  }
  __syncthreads();

  if (tid < 256) {
    int row = tid;
    float M1 = -3.4e38f, M2 = -3.4e38f;
#pragma unroll
    for (int e = 0; e < 16; ++e) {
      float2 v = redm[e * 256 + row];
      float mx2 = fmaxf(M2, v.y);
      M2 = __builtin_amdgcn_fmed3f(M1, v.x, mx2);
      M1 = fmaxf(M1, v.x);
    }
    int grow = blockIdx.x * 256 + row;
    bool flg = (M1 - M2) < TAU_M;        // uncertified -> fp64 fixup
    int code = 1023 - (int)(__float_as_uint(M1) & 0x3FFu);
    WS_FLAGS(ws)[grow] = flg ? 1 : 0;
    win[row] = flg ? -1 : code;
    if (!flg) atomicAdd(&WS_COUNTS(ws)[code], 1);
  }
  __syncthreads();

  // gather + quantized_st + sse (4 threads/row, coalesced; skip flagged rows)
  float ssep = 0.f;
  {
    int row = tid >> 2, qtr = tid & 3;
    int wv = win[row];
    if (wv >= 0) {
      size_t grow = (size_t)blockIdx.x * 256 + row;
      const float4* epg = (const float4*)(emb + (size_t)wv * DIM) + qtr * 4;
      const float4* zp  = (const float4*)(z + grow * DIM) + qtr * 4;
      float4* op = (float4*)(outp + grow * DIM) + qtr * 4;
#pragma unroll
      for (int j = 0; j < 4; ++j) {
        float4 e = epg[j], zz = zp[j];
        float4 qv;
        qv.x = zz.x + (e.x - zz.x); qv.y = zz.y + (e.y - zz.y);
        qv.z = zz.z + (e.z - zz.z); qv.w = zz.w + (e.w - zz.w);
        op[j] = qv;
        float dx = zz.x - e.x, dy = zz.y - e.y, dz = zz.z - e.z, dw = zz.w - e.w;
        ssep += dx * dx + dy * dy + dz * dz + dw * dw;
      }
    }
  }
  for (int off = 32; off; off >>= 1) ssep += __shfl_down(ssep, off, 64);
  if (lane == 0) ssew[w] = ssep;
  __syncthreads();
  if (tid == 0) {
    float ts = 0.f;
#pragma unroll
    for (int i = 0; i < 16; ++i) ts += ssew[i];
    atomicAdd(WS_SSE(ws), ts);
  }
}

// --------------------------------------------------------------- fixup ----
// fp64 full re-score of flagged rows; writes their out rows, counts, sse.
__global__ __launch_bounds__(256) void vq_fixup(const float* __restrict__ z,
                                                const float* __restrict__ emb,
                                                void* ws,
                                                float* __restrict__ out) {
  const int CH = NROWS / 1024;   // 64 rows per block, grid = 1024
  int base = blockIdx.x * CH;
  int tid = threadIdx.x;

  __shared__ int list[CH];
  __shared__ int nlist;
  __shared__ __align__(16) float zrow[DIM];
  __shared__ double rd[256];
  __shared__ int    ri[256];

  if (tid == 0) nlist = 0;
  __syncthreads();
  if (tid < CH && WS_FLAGS(ws)[base + tid]) {
    int p = atomicAdd(&nlist, 1);
    list[p] = base + tid;
  }
  __syncthreads();
  int n = nlist;

  for (int q = 0; q < n; ++q) {
    int row = list[q];
    if (tid < 16) *(float4*)&zrow[tid * 4] = ((const float4*)(z + (size_t)row * DIM))[tid];
    __syncthreads();

    double bd = 1e300; int bi = 0x7fffffff;
    for (int c = tid; c < KCODE; c += 256) {
      const float4* e4 = (const float4*)(emb + (size_t)c * DIM);
      double dot = 0.0, e2 = 0.0;
#pragma unroll
      for (int t = 0; t < 16; ++t) {
        float4 v = e4[t];
        float4 zz = *(const float4*)&zrow[t * 4];
        dot = fma((double)zz.x, (double)v.x, dot);
        dot = fma((double)zz.y, (double)v.y, dot);
        dot = fma((double)zz.z, (double)v.z, dot);
        dot = fma((double)zz.w, (double)v.w, dot);
        e2  = fma((double)v.x, (double)v.x, e2);
        e2  = fma((double)v.y, (double)v.y, e2);
        e2  = fma((double)v.z, (double)v.z, e2);
        e2  = fma((double)v.w, (double)v.w, e2);
      }
      double dist = e2 - 2.0 * dot;
      if (dist < bd || (dist == bd && c < bi)) { bd = dist; bi = c; }
    }
    rd[tid] = bd; ri[tid] = bi;
    __syncthreads();
    for (int st = 128; st; st >>= 1) {
      if (tid < st) {
        double od = rd[tid + st]; int oi = ri[tid + st];
        if (od < rd[tid] || (od == rd[tid] && oi < ri[tid])) { rd[tid] = od; ri[tid] = oi; }
      }
      __syncthreads();
    }
    int wi = ri[0];
    if (tid < 16) {
      float4 e  = ((const float4*)(emb + (size_t)wi * DIM))[tid];
      float4 zz = *(const float4*)&zrow[tid * 4];
      float4 qv;
      qv.x = zz.x + (e.x - zz.x); qv.y = zz.y + (e.y - zz.y);
      qv.z = zz.z + (e.z - zz.z); qv.w = zz.w + (e.w - zz.w);
      ((float4*)(out + (size_t)row * DIM))[tid] = qv;
      float dx = zz.x - e.x, dy = zz.y - e.y, dz = zz.z - e.z, dw = zz.w - e.w;
      float part = dx * dx + dy * dy + dz * dz + dw * dw;
      part += __shfl_down(part, 8, 64);
      part += __shfl_down(part, 4, 64);
      part += __shfl_down(part, 2, 64);
      part += __shfl_down(part, 1, 64);
      if (tid == 0) {
        atomicAdd(WS_SSE(ws), part);
        atomicAdd(&WS_COUNTS(ws)[wi], 1);
      }
    }
    __syncthreads();
  }
}

// ------------------------------------------------------------ finalize ----
__global__ __launch_bounds__(256) void vq_finalize(void* ws, float* __restrict__ out) {
  int tid = threadIdx.x;
  __shared__ float w4[4];
  float part = 0.f;
  for (int c = tid; c < KCODE; c += 256) {
    float p = (float)WS_COUNTS(ws)[c] * (1.0f / (float)NROWS);
    part += p * logf(p + 1e-10f);
  }
  for (int off = 32; off; off >>= 1) part += __shfl_down(part, off, 64);
  if ((tid & 63) == 0) w4[tid >> 6] = part;
  __syncthreads();
  if (tid == 0) {
    float ent = (w4[0] + w4[1]) + (w4[2] + w4[3]);
    float perp = expf(-ent);
    perp = fminf(perp, (float)KCODE);
    if (!isfinite(perp)) perp = 0.f;
    out[(size_t)NROWS * DIM]     = 0.25f * (*WS_SSE(ws)) / (float)((size_t)NROWS * DIM);
    out[(size_t)NROWS * DIM + 1] = perp;
  }
}

extern "C" void kernel_launch(void* const* d_in, const int* in_sizes, int n_in,
                              void* d_out, int out_size, void* d_ws, size_t ws_size,
                              hipStream_t stream) {
  const float* z   = (const float*)d_in[0];
  const float* emb = (const float*)d_in[1];
  float* out = (float*)d_out;
  (void)in_sizes; (void)n_in; (void)out_size; (void)ws_size;

  vq_init    <<<64,   256,  0, stream>>>(emb, d_ws);
  vq_main    <<<NROWS / 256, 1024, 0, stream>>>(z, emb, d_ws, out);
  vq_fixup   <<<1024, 256,  0, stream>>>(z, emb, d_ws, out);
  vq_finalize<<<1,    256,  0, stream>>>(d_ws, out);
}

// Round 6
// 146.555 us; speedup vs baseline: 1.0605x; 1.0605x over previous
//
#include <hip/hip_runtime.h>
#include <math.h>

#define NROWS 65536      // B*T
#define DIM   64
#define KCODE 1024
#define TAU_M 4e-2f      // packed-margin threshold (covers |m|<256 truncation + split err)

typedef __attribute__((ext_vector_type(8))) short short8;
typedef __bf16 bf16_t;
typedef bf16_t bf16x8 __attribute__((ext_vector_type(8)));
typedef __attribute__((ext_vector_type(4))) float f32x4;

union B8 { bf16x8 v; short8 s; ushort u[8]; };

// ws layout (bytes):
//   [0      .. 262143]  ushort emb_frag  (64 tiles x 4KB: ks0hi,ks0lo,ks1hi,ks1lo x lane*16B)
//   [262144 .. 266239]  float  e2h[1024]  = -(||e||^2 - 64) / 2   (shifted: argmin-invariant)
//   [266240 .. 270335]  int    counts[1024]
//   [270336 .. 270339]  float  sse
//   [270352 .. 335887]  uchar  flags[NROWS]
#define WS_EMBF(ws)   ((ushort*)(ws))
#define WS_E2H(ws)    ((float*)((char*)(ws) + 262144))
#define WS_COUNTS(ws) ((int*)((char*)(ws) + 266240))
#define WS_SSE(ws)    ((float*)((char*)(ws) + 270336))
#define WS_FLAGS(ws)  ((unsigned char*)(ws) + 270352)

__device__ __forceinline__ ushort f2bf(float x) {
  unsigned u = __float_as_uint(x);
  u += 0x7FFFu + ((u >> 16) & 1u);           // RNE
  return (ushort)(u >> 16);
}
__device__ __forceinline__ float bf2f(ushort h) {
  return __uint_as_float(((unsigned)h) << 16);
}

__device__ __forceinline__ void gload16(const int4* g, int4* l) {
  __builtin_amdgcn_global_load_lds((const __attribute__((address_space(1))) void*)g,
                                   (__attribute__((address_space(3))) void*)l, 16, 0, 0);
}

// ---------------------------------------------------------------- init ----
// grid 64 blocks x 256 threads; block = one 16-code tile (4KB fragment image).
__global__ __launch_bounds__(256) void vq_init(const float* __restrict__ emb, void* ws) {
  __shared__ __align__(16) ushort timg[2048];   // 4KB tile image
  __shared__ float e2p[256];

  const int g = blockIdx.x, t = threadIdx.x;    // g = global tile (16 codes)
  const int cl = t & 15;                        // local code (= MFMA col)
  const int d0 = (t >> 4) * 4;                  // dim range start
  const int gc = g * 16 + cl;

  const float4 v = *(const float4*)(emb + (size_t)gc * DIM + d0);
  float xs[4] = {v.x, v.y, v.z, v.w};
  float acc = 0.f;
#pragma unroll
  for (int u = 0; u < 4; ++u) {
    int d = d0 + u;
    float x = xs[u];
    ushort hs = f2bf(x);
    ushort ls = f2bf(x - bf2f(hs));
    int ks = d >> 5, kq = (d >> 3) & 3, e = d & 7;
    int lane = cl + kq * 16;
    int off = ks * 1024 + lane * 8 + e;         // ushort units within tile image
    timg[off] = hs;
    timg[off + 512] = ls;
    acc += x * x;
  }
  e2p[t] = acc;
  __syncthreads();
  if (t < 16) {
    float s = 0.f;
#pragma unroll
    for (int j = 0; j < 16; ++j) s += e2p[t + 16 * j];
    WS_E2H(ws)[g * 16 + t] = -0.5f * (s - 64.0f);   // shifted offset
    WS_COUNTS(ws)[g * 16 + t] = 0;
  }
  if (g == 0 && t == 0) *WS_SSE(ws) = 0.f;
  __syncthreads();
  ((int4*)WS_EMBF(ws))[g * 256 + t] = ((const int4*)timg)[t];
}

// ---------------------------------------------------------------- main ----
// 256 threads = 4 waves; all waves share the block's 64 rows (A-frags in regs),
// codes split 4-way (wave cg owns codes cg*256..+256 = 16 tiles).
// Per-wave private triple-buffered 4KB tile staging via global_load_lds with
// counted vmcnt waits -> NO barriers in the main loop. grid = 1024 (3 blk/CU).
__global__ __launch_bounds__(256, 3) void vq_main(const float* __restrict__ z,
                                                  const float* __restrict__ emb,
                                                  void* ws,
                                                  float* __restrict__ outp) {
  __shared__ __align__(16) int4 ebuf[4][3][256];   // [cg][tri-buf][4KB tile]  48KB
  __shared__ float e2s[KCODE];                     // 4KB

  const int tid  = threadIdx.x;
  const int lane = tid & 63, cg = tid >> 6;
  const int col  = lane & 15, kq = lane >> 4;
  const int rowbase = blockIdx.x * 64;
  const int cgbase  = cg * 256;
  const int invBase = 1023 - cgbase - col;

  // stage e2h -> LDS (4KB)
  ((float4*)e2s)[tid] = ((const float4*)WS_E2H(ws))[tid];

  // A fragments: 4 row-groups-of-16 x 2 ksteps, hi+lo, in registers all kernel.
  // Also per-row ||z||^2 partials (16 dims/lane, completed via shfl over kq).
  B8 ah[4][2], al[4][2];
  float z2p[4];
#pragma unroll
  for (int g = 0; g < 4; ++g) {
    int row = rowbase + g * 16 + col;
    const float* zr = z + (size_t)row * DIM;
    float acc2 = 0.f;
#pragma unroll
    for (int ks = 0; ks < 2; ++ks) {
      const float4* p = (const float4*)(zr + ks * 32 + kq * 8);
      float4 x0 = p[0], x1 = p[1];
      float vv[8] = {x0.x, x0.y, x0.z, x0.w, x1.x, x1.y, x1.z, x1.w};
#pragma unroll
      for (int e = 0; e < 8; ++e) {
        ushort hs = f2bf(vv[e]);
        ah[g][ks].u[e] = hs;
        al[g][ks].u[e] = f2bf(vv[e] - bf2f(hs));
        acc2 = fmaf(vv[e], vv[e], acc2);
      }
    }
    z2p[g] = acc2;
  }
#pragma unroll
  for (int g = 0; g < 4; ++g) {
    z2p[g] += __shfl_xor(z2p[g], 16, 64);
    z2p[g] += __shfl_xor(z2p[g], 32, 64);
  }

  float b1[16], b2[16];   // packed top-2 of m = z.e - (e^2-64)/2 (idx in low 10 bits)
#pragma unroll
  for (int q = 0; q < 16; ++q) { b1[q] = -3.4e38f; b2[q] = -3.4e38f; }

  __syncthreads();        // e2s ready; vmcnt drained -> counted waits start clean

  const int4* img = (const int4*)WS_EMBF(ws);

#define STAGE(T, J) do {                                          \
    const int4* _s = img + (size_t)(cgbase / 16 + (T)) * 256 + lane; \
    int4* _d = &ebuf[cg][(J)][lane];                              \
    gload16(_s,       _d);                                        \
    gload16(_s + 64,  _d + 64);                                   \
    gload16(_s + 128, _d + 128);                                  \
    gload16(_s + 192, _d + 192);                                  \
  } while (0)

#define TILE(T, TB) do {                                                        \
    const char* bb = (const char*)&ebuf[cg][(TB)][0] + lane * 16;               \
    B8 bh0, bl0, bh1, bl1;                                                      \
    bh0.s = *(const short8*)(bb);                                               \
    bl0.s = *(const short8*)(bb + 1024);                                        \
    bh1.s = *(const short8*)(bb + 2048);                                        \
    bl1.s = *(const short8*)(bb + 3072);                                        \
    float cinit = e2s[cgbase + (T) * 16 + col];                                 \
    f32x4 cc = {cinit, cinit, cinit, cinit};                                    \
    int invc = invBase - (T) * 16;                                              \
    f32x4 a0 = __builtin_amdgcn_mfma_f32_16x16x32_bf16(ah[0][0].v, bh0.v, cc, 0, 0, 0); \
    f32x4 a1 = __builtin_amdgcn_mfma_f32_16x16x32_bf16(ah[1][0].v, bh0.v, cc, 0, 0, 0); \
    f32x4 a2 = __builtin_amdgcn_mfma_f32_16x16x32_bf16(ah[2][0].v, bh0.v, cc, 0, 0, 0); \
    f32x4 a3 = __builtin_amdgcn_mfma_f32_16x16x32_bf16(ah[3][0].v, bh0.v, cc, 0, 0, 0); \
    a0 = __builtin_amdgcn_mfma_f32_16x16x32_bf16(al[0][0].v, bh0.v, a0, 0, 0, 0); \
    a1 = __builtin_amdgcn_mfma_f32_16x16x32_bf16(al[1][0].v, bh0.v, a1, 0, 0, 0); \
    a2 = __builtin_amdgcn_mfma_f32_16x16x32_bf16(al[2][0].v, bh0.v, a2, 0, 0, 0); \
    a3 = __builtin_amdgcn_mfma_f32_16x16x32_bf16(al[3][0].v, bh0.v, a3, 0, 0, 0); \
    a0 = __builtin_amdgcn_mfma_f32_16x16x32_bf16(ah[0][0].v, bl0.v, a0, 0, 0, 0); \
    a1 = __builtin_amdgcn_mfma_f32_16x16x32_bf16(ah[1][0].v, bl0.v, a1, 0, 0, 0); \
    a2 = __builtin_amdgcn_mfma_f32_16x16x32_bf16(ah[2][0].v, bl0.v, a2, 0, 0, 0); \
    a3 = __builtin_amdgcn_mfma_f32_16x16x32_bf16(ah[3][0].v, bl0.v, a3, 0, 0, 0); \
    a0 = __builtin_amdgcn_mfma_f32_16x16x32_bf16(ah[0][1].v, bh1.v, a0, 0, 0, 0); \
    a1 = __builtin_amdgcn_mfma_f32_16x16x32_bf16(ah[1][1].v, bh1.v, a1, 0, 0, 0); \
    a2 = __builtin_amdgcn_mfma_f32_16x16x32_bf16(ah[2][1].v, bh1.v, a2, 0, 0, 0); \
    a3 = __builtin_amdgcn_mfma_f32_16x16x32_bf16(ah[3][1].v, bh1.v, a3, 0, 0, 0); \
    a0 = __builtin_amdgcn_mfma_f32_16x16x32_bf16(al[0][1].v, bh1.v, a0, 0, 0, 0); \
    a1 = __builtin_amdgcn_mfma_f32_16x16x32_bf16(al[1][1].v, bh1.v, a1, 0, 0, 0); \
    a2 = __builtin_amdgcn_mfma_f32_16x16x32_bf16(al[2][1].v, bh1.v, a2, 0, 0, 0); \
    a3 = __builtin_amdgcn_mfma_f32_16x16x32_bf16(al[3][1].v, bh1.v, a3, 0, 0, 0); \
    a0 = __builtin_amdgcn_mfma_f32_16x16x32_bf16(ah[0][1].v, bl1.v, a0, 0, 0, 0); \
    a1 = __builtin_amdgcn_mfma_f32_16x16x32_bf16(ah[1][1].v, bl1.v, a1, 0, 0, 0); \
    a2 = __builtin_amdgcn_mfma_f32_16x16x32_bf16(ah[2][1].v, bl1.v, a2, 0, 0, 0); \
    a3 = __builtin_amdgcn_mfma_f32_16x16x32_bf16(ah[3][1].v, bl1.v, a3, 0, 0, 0); \
    f32x4 av[4] = {a0, a1, a2, a3};                                             \
    _Pragma("unroll")                                                           \
    for (int g = 0; g < 4; ++g)                                                 \
      _Pragma("unroll")                                                         \
      for (int r = 0; r < 4; ++r) {                                             \
        int q = g * 4 + r;                                                      \
        unsigned mb = (__float_as_uint(av[g][r]) & 0xFFFFFC00u) | (unsigned)invc; \
        float mp = __uint_as_float(mb);                                         \
        float nb2 = __builtin_amdgcn_fmed3f(mp, b1[q], b2[q]);                  \
        b1[q] = fmaxf(b1[q], mp);                                               \
        b2[q] = nb2;                                                            \
      }                                                                         \
  } while (0)

  // prologue: tiles 0,1 -> bufs 0,1  (8 gloads outstanding)
  STAGE(0, 0);
  STAGE(1, 1);

  int tb = 0, pb = 2;
#pragma unroll 1
  for (int t = 0; t < 14; ++t) {
    asm volatile("s_waitcnt vmcnt(4)" ::: "memory");   // tile t's 4 loads done
    __builtin_amdgcn_sched_barrier(0);
    STAGE(t + 2, pb);                                  // outstanding back to 8
    TILE(t, tb);
    tb = (tb == 2) ? 0 : tb + 1;
    pb = (pb == 2) ? 0 : pb + 1;
  }
  asm volatile("s_waitcnt vmcnt(4)" ::: "memory");
  __builtin_amdgcn_sched_barrier(0);
  TILE(14, tb);
  tb = (tb == 2) ? 0 : tb + 1;
  asm volatile("s_waitcnt vmcnt(0)" ::: "memory");
  __builtin_amdgcn_sched_barrier(0);
  TILE(15, tb);

#undef STAGE
#undef TILE

  // per-wave top-2 merge across the 16 col-lanes (same kq)
#pragma unroll
  for (int q = 0; q < 16; ++q) {
    float m1 = b1[q], m2 = b2[q];
#pragma unroll
    for (int off = 1; off <= 8; off <<= 1) {
      float om1 = __shfl_xor(m1, off, 64);
      float om2 = __shfl_xor(m2, off, 64);
      float mx2 = fmaxf(m2, om2);
      m2 = __builtin_amdgcn_fmed3f(m1, om1, mx2);
      m1 = fmaxf(m1, om1);
    }
    b1[q] = m1; b2[q] = m2;
  }

  __syncthreads();   // all waves done with ebuf -> carve merge scratch from it
  float2* redm = (float2*)&ebuf[0][0][0];   // [cg][64 rows]   2KB
  float*  z2l  = (float*)(redm + 256);      // [64]            256B
  int*    win  = (int*)(z2l + 64);          // [64]            256B

  if (col == 0) {
#pragma unroll
    for (int q = 0; q < 16; ++q) {
      int row = (q >> 2) * 16 + kq * 4 + (q & 3);
      redm[cg * 64 + row] = make_float2(b1[q], b2[q]);
    }
  }
  if (cg == 0 && kq == 0) {
#pragma unroll
    for (int g = 0; g < 4; ++g) z2l[g * 16 + col] = z2p[g];
  }
  __syncthreads();

  if (tid < 64) {
    int row = tid;
    float M1 = -3.4e38f, M2 = -3.4e38f;
#pragma unroll
    for (int e = 0; e < 4; ++e) {
      float2 v = redm[e * 64 + row];
      float mx2 = fmaxf(M2, v.y);
      M2 = __builtin_amdgcn_fmed3f(M1, v.x, mx2);
      M1 = fmaxf(M1, v.x);
    }
    int grow = blockIdx.x * 64 + row;
    bool flg = (M1 - M2) < TAU_M;          // uncertified -> fp64 fixup
    int code = 1023 - (int)(__float_as_uint(M1) & 0x3FFu);
    WS_FLAGS(ws)[grow] = flg ? 1 : 0;
    win[row] = flg ? -1 : code;
    if (!flg) atomicAdd(&WS_COUNTS(ws)[code], 1);
    // ||z-e||^2 = ||z||^2 + 64 - 2*m1  (m1 packed; err ~1e-2/row, random sign)
    float ssep = flg ? 0.f : (z2l[row] + 64.0f - 2.0f * M1);
#pragma unroll
    for (int off = 32; off; off >>= 1) ssep += __shfl_down(ssep, off, 64);
    if (tid == 0) atomicAdd(WS_SSE(ws), ssep);
  }
  __syncthreads();

  // quantized_st == emb[winner] in value: write gather directly, no z re-read
  {
    int row = tid >> 2, qtr = tid & 3;
    int wv = win[row];
    if (wv >= 0) {
      size_t grow = (size_t)blockIdx.x * 64 + row;
      const float4* ep = (const float4*)(emb + (size_t)wv * DIM) + qtr * 4;
      float4* op = (float4*)(outp + grow * DIM) + qtr * 4;
      op[0] = ep[0]; op[1] = ep[1]; op[2] = ep[2]; op[3] = ep[3];
    }
  }
}

// --------------------------------------------------------------- fixup ----
// fp64 full re-score of flagged rows; writes their out rows, counts, sse.
__global__ __launch_bounds__(256) void vq_fixup(const float* __restrict__ z,
                                                const float* __restrict__ emb,
                                                void* ws,
                                                float* __restrict__ out) {
  const int CH = NROWS / 1024;   // 64 rows per block, grid = 1024
  int base = blockIdx.x * CH;
  int tid = threadIdx.x;

  __shared__ int list[CH];
  __shared__ int nlist;
  __shared__ __align__(16) float zrow[DIM];
  __shared__ double rd[256];
  __shared__ int    ri[256];

  if (tid == 0) nlist = 0;
  __syncthreads();
  if (tid < CH && WS_FLAGS(ws)[base + tid]) {
    int p = atomicAdd(&nlist, 1);
    list[p] = base + tid;
  }
  __syncthreads();
  int n = nlist;

  for (int q = 0; q < n; ++q) {
    int row = list[q];
    if (tid < 16) *(float4*)&zrow[tid * 4] = ((const float4*)(z + (size_t)row * DIM))[tid];
    __syncthreads();

    double bd = 1e300; int bi = 0x7fffffff;
    for (int c = tid; c < KCODE; c += 256) {
      const float4* e4 = (const float4*)(emb + (size_t)c * DIM);
      double dot = 0.0, e2 = 0.0;
#pragma unroll
      for (int t = 0; t < 16; ++t) {
        float4 v = e4[t];
        float4 zz = *(const float4*)&zrow[t * 4];
        dot = fma((double)zz.x, (double)v.x, dot);
        dot = fma((double)zz.y, (double)v.y, dot);
        dot = fma((double)zz.z, (double)v.z, dot);
        dot = fma((double)zz.w, (double)v.w, dot);
        e2  = fma((double)v.x, (double)v.x, e2);
        e2  = fma((double)v.y, (double)v.y, e2);
        e2  = fma((double)v.z, (double)v.z, e2);
        e2  = fma((double)v.w, (double)v.w, e2);
      }
      double dist = e2 - 2.0 * dot;
      if (dist < bd || (dist == bd && c < bi)) { bd = dist; bi = c; }
    }
    rd[tid] = bd; ri[tid] = bi;
    __syncthreads();
    for (int st = 128; st; st >>= 1) {
      if (tid < st) {
        double od = rd[tid + st]; int oi = ri[tid + st];
        if (od < rd[tid] || (od == rd[tid] && oi < ri[tid])) { rd[tid] = od; ri[tid] = oi; }
      }
      __syncthreads();
    }
    int wi = ri[0];
    if (tid < 16) {
      float4 e  = ((const float4*)(emb + (size_t)wi * DIM))[tid];
      float4 zz = *(const float4*)&zrow[tid * 4];
      float4 qv;
      qv.x = zz.x + (e.x - zz.x); qv.y = zz.y + (e.y - zz.y);
      qv.z = zz.z + (e.z - zz.z); qv.w = zz.w + (e.w - zz.w);
      ((float4*)(out + (size_t)row * DIM))[tid] = qv;
      float dx = zz.x - e.x, dy = zz.y - e.y, dz = zz.z - e.z, dw = zz.w - e.w;
      float part = dx * dx + dy * dy + dz * dz + dw * dw;
      part += __shfl_down(part, 8, 64);
      part += __shfl_down(part, 4, 64);
      part += __shfl_down(part, 2, 64);
      part += __shfl_down(part, 1, 64);
      if (tid == 0) {
        atomicAdd(WS_SSE(ws), part);
        atomicAdd(&WS_COUNTS(ws)[wi], 1);
      }
    }
    __syncthreads();
  }
}

// ------------------------------------------------------------ finalize ----
__global__ __launch_bounds__(256) void vq_finalize(void* ws, float* __restrict__ out) {
  int tid = threadIdx.x;
  __shared__ float w4[4];
  float part = 0.f;
  for (int c = tid; c < KCODE; c += 256) {
    float p = (float)WS_COUNTS(ws)[c] * (1.0f / (float)NROWS);
    part += p * logf(p + 1e-10f);
  }
  for (int off = 32; off; off >>= 1) part += __shfl_down(part, off, 64);
  if ((tid & 63) == 0) w4[tid >> 6] = part;
  __syncthreads();
  if (tid == 0) {
    float ent = (w4[0] + w4[1]) + (w4[2] + w4[3]);
    float perp = expf(-ent);
    perp = fminf(perp, (float)KCODE);
    if (!isfinite(perp)) perp = 0.f;
    out[(size_t)NROWS * DIM]     = 0.25f * (*WS_SSE(ws)) / (float)((size_t)NROWS * DIM);
    out[(size_t)NROWS * DIM + 1] = perp;
  }
}

extern "C" void kernel_launch(void* const* d_in, const int* in_sizes, int n_in,
                              void* d_out, int out_size, void* d_ws, size_t ws_size,
                              hipStream_t stream) {
  const float* z   = (const float*)d_in[0];
  const float* emb = (const float*)d_in[1];
  float* out = (float*)d_out;
  (void)in_sizes; (void)n_in; (void)out_size; (void)ws_size;

  vq_init    <<<64,   256, 0, stream>>>(emb, d_ws);
  vq_main    <<<NROWS / 64, 256, 0, stream>>>(z, emb, d_ws, out);
  vq_fixup   <<<1024, 256, 0, stream>>>(z, emb, d_ws, out);
  vq_finalize<<<1,    256, 0, stream>>>(d_ws, out);
}

// Round 7
// 89.936 us; speedup vs baseline: 1.7282x; 1.6296x over previous
//
#include <hip/hip_runtime.h>
#include <math.h>

#define NROWS 65536      // B*T
#define DIM   64
#define KCODE 1024
#define TAU_M 2.5e-3f    // margin threshold: eps ~5.5e-4 (split+accum+4bit-trunc), 2.3x headroom

typedef __attribute__((ext_vector_type(8))) short short8;
typedef __bf16 bf16_t;
typedef bf16_t bf16x8 __attribute__((ext_vector_type(8)));
typedef __attribute__((ext_vector_type(4))) float f32x4;

union B8 { bf16x8 v; short8 s; ushort u[8]; };

// ws layout (bytes):
//   [0      .. 262143]  ushort emb_frag  (64 tiles x 4KB: ks0hi,ks0lo,ks1hi,ks1lo x lane*16B)
//   [262144 .. 266239]  float  e2h[1024]  = -(||e||^2 - 64) / 2   (shifted: argmin-invariant)
//   [266240 .. 270335]  int    counts[1024]
//   [270336 .. 270339]  float  sse
//   [270352 .. 270355]  uint   nflag
//   [270356 .. 401427]  ushort list[NROWS]  (flagged row ids, compacted)
#define WS_EMBF(ws)   ((ushort*)(ws))
#define WS_E2H(ws)    ((float*)((char*)(ws) + 262144))
#define WS_COUNTS(ws) ((int*)((char*)(ws) + 266240))
#define WS_SSE(ws)    ((float*)((char*)(ws) + 270336))
#define WS_NFLAG(ws)  ((unsigned int*)((char*)(ws) + 270352))
#define WS_LIST(ws)   ((ushort*)((char*)(ws) + 270356))

__device__ __forceinline__ ushort f2bf(float x) {
  unsigned u = __float_as_uint(x);
  u += 0x7FFFu + ((u >> 16) & 1u);           // RNE
  return (ushort)(u >> 16);
}
__device__ __forceinline__ float bf2f(ushort h) {
  return __uint_as_float(((unsigned)h) << 16);
}

__device__ __forceinline__ void gload16(const int4* g, int4* l) {
  __builtin_amdgcn_global_load_lds((const __attribute__((address_space(1))) void*)g,
                                   (__attribute__((address_space(3))) void*)l, 16, 0, 0);
}

// ---------------------------------------------------------------- init ----
// grid 64 blocks x 256 threads; block = one 16-code tile (4KB fragment image).
__global__ __launch_bounds__(256) void vq_init(const float* __restrict__ emb, void* ws) {
  __shared__ __align__(16) ushort timg[2048];   // 4KB tile image
  __shared__ float e2p[256];

  const int g = blockIdx.x, t = threadIdx.x;    // g = global tile (16 codes)
  const int cl = t & 15;                        // local code (= MFMA col)
  const int d0 = (t >> 4) * 4;                  // dim range start
  const int gc = g * 16 + cl;

  const float4 v = *(const float4*)(emb + (size_t)gc * DIM + d0);
  float xs[4] = {v.x, v.y, v.z, v.w};
  float acc = 0.f;
#pragma unroll
  for (int u = 0; u < 4; ++u) {
    int d = d0 + u;
    float x = xs[u];
    ushort hs = f2bf(x);
    ushort ls = f2bf(x - bf2f(hs));
    int ks = d >> 5, kq = (d >> 3) & 3, e = d & 7;
    int lane = cl + kq * 16;
    int off = ks * 1024 + lane * 8 + e;         // ushort units within tile image
    timg[off] = hs;
    timg[off + 512] = ls;
    acc += x * x;
  }
  e2p[t] = acc;
  __syncthreads();
  if (t < 16) {
    float s = 0.f;
#pragma unroll
    for (int j = 0; j < 16; ++j) s += e2p[t + 16 * j];
    WS_E2H(ws)[g * 16 + t] = -0.5f * (s - 64.0f);   // shifted offset
    WS_COUNTS(ws)[g * 16 + t] = 0;
  }
  if (g == 0 && t == 0) { *WS_SSE(ws) = 0.f; *WS_NFLAG(ws) = 0u; }
  __syncthreads();
  ((int4*)WS_EMBF(ws))[g * 256 + t] = ((const int4*)timg)[t];
}

// ---------------------------------------------------------------- main ----
// 256 threads = 4 waves; all waves share the block's 64 rows (A-frags in regs),
// codes split 4-way (wave cg owns codes cg*256..+256 = 16 tiles).
// Per-wave private triple-buffered 4KB tile staging via global_load_lds with
// counted vmcnt waits -> NO barriers in the main loop. grid = 1024 (3 blk/CU).
__global__ __launch_bounds__(256, 3) void vq_main(const float* __restrict__ z,
                                                  const float* __restrict__ emb,
                                                  void* ws,
                                                  float* __restrict__ outp) {
  __shared__ __align__(16) int4 ebuf[4][3][256];   // [cg][tri-buf][4KB tile]  48KB
  __shared__ float e2s[KCODE];                     // 4KB

  const int tid  = threadIdx.x;
  const int lane = tid & 63, cg = tid >> 6;
  const int col  = lane & 15, kq = lane >> 4;
  const int rowbase = blockIdx.x * 64;
  const int cgbase  = cg * 256;

  // stage e2h -> LDS (4KB)
  ((float4*)e2s)[tid] = ((const float4*)WS_E2H(ws))[tid];

  // A fragments: 4 row-groups-of-16 x 2 ksteps, hi+lo, in registers all kernel.
  // Also per-row ||z||^2 partials (16 dims/lane, completed via shfl over kq).
  B8 ah[4][2], al[4][2];
  float z2p[4];
#pragma unroll
  for (int g = 0; g < 4; ++g) {
    int row = rowbase + g * 16 + col;
    const float* zr = z + (size_t)row * DIM;
    float acc2 = 0.f;
#pragma unroll
    for (int ks = 0; ks < 2; ++ks) {
      const float4* p = (const float4*)(zr + ks * 32 + kq * 8);
      float4 x0 = p[0], x1 = p[1];
      float vv[8] = {x0.x, x0.y, x0.z, x0.w, x1.x, x1.y, x1.z, x1.w};
#pragma unroll
      for (int e = 0; e < 8; ++e) {
        ushort hs = f2bf(vv[e]);
        ah[g][ks].u[e] = hs;
        al[g][ks].u[e] = f2bf(vv[e] - bf2f(hs));
        acc2 = fmaf(vv[e], vv[e], acc2);
      }
    }
    z2p[g] = acc2;
  }
#pragma unroll
  for (int g = 0; g < 4; ++g) {
    z2p[g] += __shfl_xor(z2p[g], 16, 64);
    z2p[g] += __shfl_xor(z2p[g], 32, 64);
  }

  float b1[16], b2[16];   // packed top-2 of m = z.e - (e^2-64)/2; low 4 bits = 15-T
#pragma unroll
  for (int q = 0; q < 16; ++q) { b1[q] = -3.4e38f; b2[q] = -3.4e38f; }

  __syncthreads();        // e2s ready

  const int4* img = (const int4*)WS_EMBF(ws);

#define STAGE(T, J) do {                                          \
    const int4* _s = img + (size_t)(cgbase / 16 + (T)) * 256 + lane; \
    int4* _d = &ebuf[cg][(J)][lane];                              \
    gload16(_s,       _d);                                        \
    gload16(_s + 64,  _d + 64);                                   \
    gload16(_s + 128, _d + 128);                                  \
    gload16(_s + 192, _d + 192);                                  \
  } while (0)

#define TILE(T, TB) do {                                                        \
    const char* bb = (const char*)&ebuf[cg][(TB)][0] + lane * 16;               \
    B8 bh0, bl0, bh1, bl1;                                                      \
    bh0.s = *(const short8*)(bb);                                               \
    bl0.s = *(const short8*)(bb + 1024);                                        \
    bh1.s = *(const short8*)(bb + 2048);                                        \
    bl1.s = *(const short8*)(bb + 3072);                                        \
    float cinit = e2s[cgbase + (T) * 16 + col];                                 \
    f32x4 cc = {cinit, cinit, cinit, cinit};                                    \
    unsigned invT = 15u - (unsigned)(T);                                        \
    f32x4 a0 = __builtin_amdgcn_mfma_f32_16x16x32_bf16(ah[0][0].v, bh0.v, cc, 0, 0, 0); \
    f32x4 a1 = __builtin_amdgcn_mfma_f32_16x16x32_bf16(ah[1][0].v, bh0.v, cc, 0, 0, 0); \
    f32x4 a2 = __builtin_amdgcn_mfma_f32_16x16x32_bf16(ah[2][0].v, bh0.v, cc, 0, 0, 0); \
    f32x4 a3 = __builtin_amdgcn_mfma_f32_16x16x32_bf16(ah[3][0].v, bh0.v, cc, 0, 0, 0); \
    a0 = __builtin_amdgcn_mfma_f32_16x16x32_bf16(al[0][0].v, bh0.v, a0, 0, 0, 0); \
    a1 = __builtin_amdgcn_mfma_f32_16x16x32_bf16(al[1][0].v, bh0.v, a1, 0, 0, 0); \
    a2 = __builtin_amdgcn_mfma_f32_16x16x32_bf16(al[2][0].v, bh0.v, a2, 0, 0, 0); \
    a3 = __builtin_amdgcn_mfma_f32_16x16x32_bf16(al[3][0].v, bh0.v, a3, 0, 0, 0); \
    a0 = __builtin_amdgcn_mfma_f32_16x16x32_bf16(ah[0][0].v, bl0.v, a0, 0, 0, 0); \
    a1 = __builtin_amdgcn_mfma_f32_16x16x32_bf16(ah[1][0].v, bl0.v, a1, 0, 0, 0); \
    a2 = __builtin_amdgcn_mfma_f32_16x16x32_bf16(ah[2][0].v, bl0.v, a2, 0, 0, 0); \
    a3 = __builtin_amdgcn_mfma_f32_16x16x32_bf16(ah[3][0].v, bl0.v, a3, 0, 0, 0); \
    a0 = __builtin_amdgcn_mfma_f32_16x16x32_bf16(ah[0][1].v, bh1.v, a0, 0, 0, 0); \
    a1 = __builtin_amdgcn_mfma_f32_16x16x32_bf16(ah[1][1].v, bh1.v, a1, 0, 0, 0); \
    a2 = __builtin_amdgcn_mfma_f32_16x16x32_bf16(ah[2][1].v, bh1.v, a2, 0, 0, 0); \
    a3 = __builtin_amdgcn_mfma_f32_16x16x32_bf16(ah[3][1].v, bh1.v, a3, 0, 0, 0); \
    a0 = __builtin_amdgcn_mfma_f32_16x16x32_bf16(al[0][1].v, bh1.v, a0, 0, 0, 0); \
    a1 = __builtin_amdgcn_mfma_f32_16x16x32_bf16(al[1][1].v, bh1.v, a1, 0, 0, 0); \
    a2 = __builtin_amdgcn_mfma_f32_16x16x32_bf16(al[2][1].v, bh1.v, a2, 0, 0, 0); \
    a3 = __builtin_amdgcn_mfma_f32_16x16x32_bf16(al[3][1].v, bh1.v, a3, 0, 0, 0); \
    a0 = __builtin_amdgcn_mfma_f32_16x16x32_bf16(ah[0][1].v, bl1.v, a0, 0, 0, 0); \
    a1 = __builtin_amdgcn_mfma_f32_16x16x32_bf16(ah[1][1].v, bl1.v, a1, 0, 0, 0); \
    a2 = __builtin_amdgcn_mfma_f32_16x16x32_bf16(ah[2][1].v, bl1.v, a2, 0, 0, 0); \
    a3 = __builtin_amdgcn_mfma_f32_16x16x32_bf16(ah[3][1].v, bl1.v, a3, 0, 0, 0); \
    f32x4 av[4] = {a0, a1, a2, a3};                                             \
    _Pragma("unroll")                                                           \
    for (int g = 0; g < 4; ++g)                                                 \
      _Pragma("unroll")                                                         \
      for (int r = 0; r < 4; ++r) {                                             \
        int q = g * 4 + r;                                                      \
        unsigned mb = (__float_as_uint(av[g][r]) & 0xFFFFFFF0u) | invT;         \
        float mp = __uint_as_float(mb);                                         \
        float nb2 = __builtin_amdgcn_fmed3f(mp, b1[q], b2[q]);                  \
        b1[q] = fmaxf(b1[q], mp);                                               \
        b2[q] = nb2;                                                            \
      }                                                                         \
  } while (0)

  // prologue: tiles 0,1 -> bufs 0,1  (8 gloads outstanding)
  STAGE(0, 0);
  STAGE(1, 1);

  int tb = 0, pb = 2;
#pragma unroll 1
  for (int t = 0; t < 14; ++t) {
    asm volatile("s_waitcnt vmcnt(4)" ::: "memory");   // tile t's 4 loads done
    __builtin_amdgcn_sched_barrier(0);
    STAGE(t + 2, pb);                                  // outstanding back to 8
    TILE(t, tb);
    tb = (tb == 2) ? 0 : tb + 1;
    pb = (pb == 2) ? 0 : pb + 1;
  }
  asm volatile("s_waitcnt vmcnt(4)" ::: "memory");
  __builtin_amdgcn_sched_barrier(0);
  TILE(14, tb);
  tb = (tb == 2) ? 0 : tb + 1;
  asm volatile("s_waitcnt vmcnt(0)" ::: "memory");
  __builtin_amdgcn_sched_barrier(0);
  TILE(15, tb);

#undef STAGE
#undef TILE

  // unpack to explicit (m, code) and top-2 merge across the 16 col-lanes
  float m1a[16], m2a[16]; int c1a[16];
#pragma unroll
  for (int q = 0; q < 16; ++q) {
    unsigned u1 = __float_as_uint(b1[q]);
    int T1 = 15 - (int)(u1 & 0xFu);
    float m1 = __uint_as_float(u1 & 0xFFFFFFF0u);
    int   c1 = cgbase + T1 * 16 + col;
    float m2 = __uint_as_float(__float_as_uint(b2[q]) & 0xFFFFFFF0u);
#pragma unroll
    for (int off = 1; off <= 8; off <<= 1) {
      float om1 = __shfl_xor(m1, off, 64);
      float om2 = __shfl_xor(m2, off, 64);
      int   oc1 = __shfl_xor(c1, off, 64);
      bool take = (om1 > m1) || (om1 == m1 && oc1 < c1);
      m2 = __builtin_amdgcn_fmed3f(m1, om1, fmaxf(m2, om2));
      m1 = take ? om1 : m1;
      c1 = take ? oc1 : c1;
    }
    m1a[q] = m1; m2a[q] = m2; c1a[q] = c1;
  }

  __syncthreads();   // all waves done with ebuf -> carve merge scratch from it
  float2* redm = (float2*)&ebuf[0][0][0];   // [cg][64 rows]  2KB
  int*    redi = (int*)(redm + 256);        // [cg][64 rows]  1KB
  float*  z2l  = (float*)(redi + 256);      // [64]           256B
  int*    win  = (int*)(z2l + 64);          // [64]           256B

  if (col == 0) {
#pragma unroll
    for (int q = 0; q < 16; ++q) {
      int row = (q >> 2) * 16 + kq * 4 + (q & 3);
      redm[cg * 64 + row] = make_float2(m1a[q], m2a[q]);
      redi[cg * 64 + row] = c1a[q];
    }
  }
  if (cg == 0 && kq == 0) {
#pragma unroll
    for (int g = 0; g < 4; ++g) z2l[g * 16 + col] = z2p[g];
  }
  __syncthreads();

  if (tid < 64) {
    int row = tid;
    float M1 = -3.4e38f, M2 = -3.4e38f; int C1 = 0x7fffffff;
#pragma unroll
    for (int e = 0; e < 4; ++e) {
      float2 v = redm[e * 64 + row];
      int    ci = redi[e * 64 + row];
      bool take = (v.x > M1) || (v.x == M1 && ci < C1);
      M2 = __builtin_amdgcn_fmed3f(M1, v.x, fmaxf(M2, v.y));
      M1 = take ? v.x : M1;
      C1 = take ? ci : C1;
    }
    int grow = blockIdx.x * 64 + row;
    bool flg = (M1 - M2) < TAU_M;          // uncertified -> fp64 fixup
    win[row] = flg ? -1 : C1;
    if (!flg) {
      atomicAdd(&WS_COUNTS(ws)[C1], 1);
    } else {
      unsigned p = atomicAdd(WS_NFLAG(ws), 1u);
      WS_LIST(ws)[p] = (ushort)grow;
    }
    // ||z-e||^2 = ||z||^2 + 64 - 2*m1  (m1 err ~5e-4 -> loss err ~1e-6)
    float ssep = flg ? 0.f : (z2l[row] + 64.0f - 2.0f * M1);
#pragma unroll
    for (int off = 32; off; off >>= 1) ssep += __shfl_down(ssep, off, 64);
    if (tid == 0) atomicAdd(WS_SSE(ws), ssep);
  }
  __syncthreads();

  // quantized_st == emb[winner] in value: write gather directly, no z re-read
  {
    int row = tid >> 2, qtr = tid & 3;
    int wv = win[row];
    if (wv >= 0) {
      size_t grow = (size_t)blockIdx.x * 64 + row;
      const float4* ep = (const float4*)(emb + (size_t)wv * DIM) + qtr * 4;
      float4* op = (float4*)(outp + grow * DIM) + qtr * 4;
      op[0] = ep[0]; op[1] = ep[1]; op[2] = ep[2]; op[3] = ep[3];
    }
  }
}

// --------------------------------------------------------------- fixup ----
// fp64 full re-score of flagged rows from the compacted list (load-balanced
// grid-stride); writes their out rows, counts, sse.
__global__ __launch_bounds__(256) void vq_fixup(const float* __restrict__ z,
                                                const float* __restrict__ emb,
                                                void* ws,
                                                float* __restrict__ out) {
  int tid = threadIdx.x;
  __shared__ __align__(16) float zrow[DIM];
  __shared__ double rd[256];
  __shared__ int    ri[256];

  const int n = (int)*WS_NFLAG(ws);

  for (int i = blockIdx.x; i < n; i += 1024) {
    int row = (int)WS_LIST(ws)[i];
    if (tid < 16) *(float4*)&zrow[tid * 4] = ((const float4*)(z + (size_t)row * DIM))[tid];
    __syncthreads();

    double bd = 1e300; int bi = 0x7fffffff;
    for (int c = tid; c < KCODE; c += 256) {
      const float4* e4 = (const float4*)(emb + (size_t)c * DIM);
      double dot = 0.0, e2 = 0.0;
#pragma unroll
      for (int t = 0; t < 16; ++t) {
        float4 v = e4[t];
        float4 zz = *(const float4*)&zrow[t * 4];
        dot = fma((double)zz.x, (double)v.x, dot);
        dot = fma((double)zz.y, (double)v.y, dot);
        dot = fma((double)zz.z, (double)v.z, dot);
        dot = fma((double)zz.w, (double)v.w, dot);
        e2  = fma((double)v.x, (double)v.x, e2);
        e2  = fma((double)v.y, (double)v.y, e2);
        e2  = fma((double)v.z, (double)v.z, e2);
        e2  = fma((double)v.w, (double)v.w, e2);
      }
      double dist = e2 - 2.0 * dot;
      if (dist < bd || (dist == bd && c < bi)) { bd = dist; bi = c; }
    }
    rd[tid] = bd; ri[tid] = bi;
    __syncthreads();
    for (int st = 128; st; st >>= 1) {
      if (tid < st) {
        double od = rd[tid + st]; int oi = ri[tid + st];
        if (od < rd[tid] || (od == rd[tid] && oi < ri[tid])) { rd[tid] = od; ri[tid] = oi; }
      }
      __syncthreads();
    }
    int wi = ri[0];
    if (tid < 16) {
      float4 e  = ((const float4*)(emb + (size_t)wi * DIM))[tid];
      float4 zz = *(const float4*)&zrow[tid * 4];
      float4 qv;
      qv.x = zz.x + (e.x - zz.x); qv.y = zz.y + (e.y - zz.y);
      qv.z = zz.z + (e.z - zz.z); qv.w = zz.w + (e.w - zz.w);
      ((float4*)(out + (size_t)row * DIM))[tid] = qv;
      float dx = zz.x - e.x, dy = zz.y - e.y, dz = zz.z - e.z, dw = zz.w - e.w;
      float part = dx * dx + dy * dy + dz * dz + dw * dw;
      part += __shfl_down(part, 8, 64);
      part += __shfl_down(part, 4, 64);
      part += __shfl_down(part, 2, 64);
      part += __shfl_down(part, 1, 64);
      if (tid == 0) {
        atomicAdd(WS_SSE(ws), part);
        atomicAdd(&WS_COUNTS(ws)[wi], 1);
      }
    }
    __syncthreads();
  }
}

// ------------------------------------------------------------ finalize ----
__global__ __launch_bounds__(256) void vq_finalize(void* ws, float* __restrict__ out) {
  int tid = threadIdx.x;
  __shared__ float w4[4];
  float part = 0.f;
  for (int c = tid; c < KCODE; c += 256) {
    float p = (float)WS_COUNTS(ws)[c] * (1.0f / (float)NROWS);
    part += p * logf(p + 1e-10f);
  }
  for (int off = 32; off; off >>= 1) part += __shfl_down(part, off, 64);
  if ((tid & 63) == 0) w4[tid >> 6] = part;
  __syncthreads();
  if (tid == 0) {
    float ent = (w4[0] + w4[1]) + (w4[2] + w4[3]);
    float perp = expf(-ent);
    perp = fminf(perp, (float)KCODE);
    if (!isfinite(perp)) perp = 0.f;
    out[(size_t)NROWS * DIM]     = 0.25f * (*WS_SSE(ws)) / (float)((size_t)NROWS * DIM);
    out[(size_t)NROWS * DIM + 1] = perp;
  }
}

extern "C" void kernel_launch(void* const* d_in, const int* in_sizes, int n_in,
                              void* d_out, int out_size, void* d_ws, size_t ws_size,
                              hipStream_t stream) {
  const float* z   = (const float*)d_in[0];
  const float* emb = (const float*)d_in[1];
  float* out = (float*)d_out;
  (void)in_sizes; (void)n_in; (void)out_size; (void)ws_size;

  vq_init    <<<64,   256, 0, stream>>>(emb, d_ws);
  vq_main    <<<NROWS / 64, 256, 0, stream>>>(z, emb, d_ws, out);
  vq_fixup   <<<1024, 256, 0, stream>>>(z, emb, d_ws, out);
  vq_finalize<<<1,    256, 0, stream>>>(d_ws, out);
}

// Round 8
// 82.680 us; speedup vs baseline: 1.8798x; 1.0878x over previous
//
#include <hip/hip_runtime.h>
#include <math.h>

#define NROWS 65536      // B*T
#define DIM   64
#define KCODE 1024
#define TAU_M 2.5e-3f    // margin threshold: eps ~5.5e-4 (split+accum+4bit-trunc), 2.3x headroom

typedef __attribute__((ext_vector_type(8))) short short8;
typedef __bf16 bf16_t;
typedef bf16_t bf16x8 __attribute__((ext_vector_type(8)));
typedef __attribute__((ext_vector_type(4))) float f32x4;

union B8 { bf16x8 v; short8 s; ushort u[8]; };

// ws layout (bytes):
//   [0      .. 262143]  ushort emb_frag  (64 tiles x 4KB: ks0hi,ks0lo,ks1hi,ks1lo x lane*16B)
//   [262144 .. 266239]  float  e2h[1024]  = -(||e||^2 - 64) / 2   (shifted: argmin-invariant)
//   [266240 .. 270335]  int    counts[1024]
//   [270336 .. 270339]  float  sse
//   [270352 .. 270355]  uint   nflag
//   [270356 .. 401427]  ushort list[NROWS]  (flagged row ids, compacted)
#define WS_EMBF(ws)   ((ushort*)(ws))
#define WS_E2H(ws)    ((float*)((char*)(ws) + 262144))
#define WS_COUNTS(ws) ((int*)((char*)(ws) + 266240))
#define WS_SSE(ws)    ((float*)((char*)(ws) + 270336))
#define WS_NFLAG(ws)  ((unsigned int*)((char*)(ws) + 270352))
#define WS_LIST(ws)   ((ushort*)((char*)(ws) + 270356))

__device__ __forceinline__ ushort f2bf(float x) {
  unsigned u = __float_as_uint(x);
  u += 0x7FFFu + ((u >> 16) & 1u);           // RNE
  return (ushort)(u >> 16);
}
__device__ __forceinline__ float bf2f(ushort h) {
  return __uint_as_float(((unsigned)h) << 16);
}

// ---------------------------------------------------------------- init ----
// grid 64 blocks x 256 threads; block = one 16-code tile (4KB fragment image).
__global__ __launch_bounds__(256) void vq_init(const float* __restrict__ emb, void* ws) {
  __shared__ __align__(16) ushort timg[2048];   // 4KB tile image
  __shared__ float e2p[256];

  const int g = blockIdx.x, t = threadIdx.x;    // g = global tile (16 codes)
  const int cl = t & 15;                        // local code (= MFMA col)
  const int d0 = (t >> 4) * 4;                  // dim range start
  const int gc = g * 16 + cl;

  const float4 v = *(const float4*)(emb + (size_t)gc * DIM + d0);
  float xs[4] = {v.x, v.y, v.z, v.w};
  float acc = 0.f;
#pragma unroll
  for (int u = 0; u < 4; ++u) {
    int d = d0 + u;
    float x = xs[u];
    ushort hs = f2bf(x);
    ushort ls = f2bf(x - bf2f(hs));
    int ks = d >> 5, kq = (d >> 3) & 3, e = d & 7;
    int lane = cl + kq * 16;
    int off = ks * 1024 + lane * 8 + e;         // ushort units within tile image
    timg[off] = hs;
    timg[off + 512] = ls;
    acc += x * x;
  }
  e2p[t] = acc;
  __syncthreads();
  if (t < 16) {
    float s = 0.f;
#pragma unroll
    for (int j = 0; j < 16; ++j) s += e2p[t + 16 * j];
    WS_E2H(ws)[g * 16 + t] = -0.5f * (s - 64.0f);   // shifted offset
    WS_COUNTS(ws)[g * 16 + t] = 0;
  }
  if (g == 0 && t == 0) { *WS_SSE(ws) = 0.f; *WS_NFLAG(ws) = 0u; }
  __syncthreads();
  ((int4*)WS_EMBF(ws))[g * 256 + t] = ((const int4*)timg)[t];
}

// ---------------------------------------------------------------- main ----
// 256 threads = 4 waves; all waves share the block's 64 rows (A-frags in regs),
// codes split 4-way (wave cg owns codes cg*256..+256 = 16 tiles).
// B-fragments are loaded DIRECTLY from the global fragment image (lane-linear,
// coalesced dwordx4, L2-resident 256KB) into VGPRs — no LDS staging, no DMA,
// no inline-asm waits. Hot loop = global loads + MFMA + packed top-2 only.
__global__ __launch_bounds__(256, 3) void vq_main(const float* __restrict__ z,
                                                  const float* __restrict__ emb,
                                                  void* ws,
                                                  float* __restrict__ outp) {
  __shared__ float2 redm[256];   // [cg][64 rows] top-2 m
  __shared__ int    redi[256];   // [cg][64 rows] argmax code
  __shared__ float  z2l[64];
  __shared__ int    win[64];

  const int tid  = threadIdx.x;
  const int lane = tid & 63, cg = tid >> 6;
  const int col  = lane & 15, kq = lane >> 4;
  const int rowbase = blockIdx.x * 64;
  const int cgbase  = cg * 256;

  // A fragments: 4 row-groups-of-16 x 2 ksteps, hi+lo, in registers all kernel.
  // Also per-row ||z||^2 partials (16 dims/lane, completed via shfl over kq).
  B8 ah[4][2], al[4][2];
  float z2p[4];
#pragma unroll
  for (int g = 0; g < 4; ++g) {
    int row = rowbase + g * 16 + col;
    const float* zr = z + (size_t)row * DIM;
    float acc2 = 0.f;
#pragma unroll
    for (int ks = 0; ks < 2; ++ks) {
      const float4* p = (const float4*)(zr + ks * 32 + kq * 8);
      float4 x0 = p[0], x1 = p[1];
      float vv[8] = {x0.x, x0.y, x0.z, x0.w, x1.x, x1.y, x1.z, x1.w};
#pragma unroll
      for (int e = 0; e < 8; ++e) {
        ushort hs = f2bf(vv[e]);
        ah[g][ks].u[e] = hs;
        al[g][ks].u[e] = f2bf(vv[e] - bf2f(hs));
        acc2 = fmaf(vv[e], vv[e], acc2);
      }
    }
    z2p[g] = acc2;
  }
#pragma unroll
  for (int g = 0; g < 4; ++g) {
    z2p[g] += __shfl_xor(z2p[g], 16, 64);
    z2p[g] += __shfl_xor(z2p[g], 32, 64);
  }

  // C-init values for this wave's 16 tiles, preloaded to registers (no LDS)
  float cin[16];
#pragma unroll
  for (int t = 0; t < 16; ++t) cin[t] = WS_E2H(ws)[cgbase + t * 16 + col];

  float b1[16], b2[16];   // packed top-2 of m = z.e - (e^2-64)/2; low 4 bits = 15-T
#pragma unroll
  for (int q = 0; q < 16; ++q) { b1[q] = -3.4e38f; b2[q] = -3.4e38f; }

  const short8* img8 = (const short8*)WS_EMBF(ws);   // frag stride 64, tile stride 256

#pragma unroll 4
  for (int t = 0; t < 16; ++t) {
    const short8* ib = img8 + ((size_t)(cg * 16 + t) * 4) * 64 + lane;
    B8 bh0, bl0, bh1, bl1;
    bh0.s = ib[0];
    bl0.s = ib[64];
    bh1.s = ib[128];
    bl1.s = ib[192];

    float cinit = cin[t];
    f32x4 cc = {cinit, cinit, cinit, cinit};
    unsigned invT = 15u - (unsigned)t;

    f32x4 a0 = __builtin_amdgcn_mfma_f32_16x16x32_bf16(ah[0][0].v, bh0.v, cc, 0, 0, 0);
    f32x4 a1 = __builtin_amdgcn_mfma_f32_16x16x32_bf16(ah[1][0].v, bh0.v, cc, 0, 0, 0);
    f32x4 a2 = __builtin_amdgcn_mfma_f32_16x16x32_bf16(ah[2][0].v, bh0.v, cc, 0, 0, 0);
    f32x4 a3 = __builtin_amdgcn_mfma_f32_16x16x32_bf16(ah[3][0].v, bh0.v, cc, 0, 0, 0);
    a0 = __builtin_amdgcn_mfma_f32_16x16x32_bf16(al[0][0].v, bh0.v, a0, 0, 0, 0);
    a1 = __builtin_amdgcn_mfma_f32_16x16x32_bf16(al[1][0].v, bh0.v, a1, 0, 0, 0);
    a2 = __builtin_amdgcn_mfma_f32_16x16x32_bf16(al[2][0].v, bh0.v, a2, 0, 0, 0);
    a3 = __builtin_amdgcn_mfma_f32_16x16x32_bf16(al[3][0].v, bh0.v, a3, 0, 0, 0);
    a0 = __builtin_amdgcn_mfma_f32_16x16x32_bf16(ah[0][0].v, bl0.v, a0, 0, 0, 0);
    a1 = __builtin_amdgcn_mfma_f32_16x16x32_bf16(ah[1][0].v, bl0.v, a1, 0, 0, 0);
    a2 = __builtin_amdgcn_mfma_f32_16x16x32_bf16(ah[2][0].v, bl0.v, a2, 0, 0, 0);
    a3 = __builtin_amdgcn_mfma_f32_16x16x32_bf16(ah[3][0].v, bl0.v, a3, 0, 0, 0);
    a0 = __builtin_amdgcn_mfma_f32_16x16x32_bf16(ah[0][1].v, bh1.v, a0, 0, 0, 0);
    a1 = __builtin_amdgcn_mfma_f32_16x16x32_bf16(ah[1][1].v, bh1.v, a1, 0, 0, 0);
    a2 = __builtin_amdgcn_mfma_f32_16x16x32_bf16(ah[2][1].v, bh1.v, a2, 0, 0, 0);
    a3 = __builtin_amdgcn_mfma_f32_16x16x32_bf16(ah[3][1].v, bh1.v, a3, 0, 0, 0);
    a0 = __builtin_amdgcn_mfma_f32_16x16x32_bf16(al[0][1].v, bh1.v, a0, 0, 0, 0);
    a1 = __builtin_amdgcn_mfma_f32_16x16x32_bf16(al[1][1].v, bh1.v, a1, 0, 0, 0);
    a2 = __builtin_amdgcn_mfma_f32_16x16x32_bf16(al[2][1].v, bh1.v, a2, 0, 0, 0);
    a3 = __builtin_amdgcn_mfma_f32_16x16x32_bf16(al[3][1].v, bh1.v, a3, 0, 0, 0);
    a0 = __builtin_amdgcn_mfma_f32_16x16x32_bf16(ah[0][1].v, bl1.v, a0, 0, 0, 0);
    a1 = __builtin_amdgcn_mfma_f32_16x16x32_bf16(ah[1][1].v, bl1.v, a1, 0, 0, 0);
    a2 = __builtin_amdgcn_mfma_f32_16x16x32_bf16(ah[2][1].v, bl1.v, a2, 0, 0, 0);
    a3 = __builtin_amdgcn_mfma_f32_16x16x32_bf16(ah[3][1].v, bl1.v, a3, 0, 0, 0);

    f32x4 av[4] = {a0, a1, a2, a3};
#pragma unroll
    for (int g = 0; g < 4; ++g)
#pragma unroll
      for (int r = 0; r < 4; ++r) {
        int q = g * 4 + r;
        unsigned mb = (__float_as_uint(av[g][r]) & 0xFFFFFFF0u) | invT;
        float mp = __uint_as_float(mb);
        float nb2 = __builtin_amdgcn_fmed3f(mp, b1[q], b2[q]);
        b1[q] = fmaxf(b1[q], mp);
        b2[q] = nb2;
      }
  }

  // unpack to explicit (m, code) and top-2 merge across the 16 col-lanes
  float m1a[16], m2a[16]; int c1a[16];
#pragma unroll
  for (int q = 0; q < 16; ++q) {
    unsigned u1 = __float_as_uint(b1[q]);
    int T1 = 15 - (int)(u1 & 0xFu);
    float m1 = __uint_as_float(u1 & 0xFFFFFFF0u);
    int   c1 = cgbase + T1 * 16 + col;
    float m2 = __uint_as_float(__float_as_uint(b2[q]) & 0xFFFFFFF0u);
#pragma unroll
    for (int off = 1; off <= 8; off <<= 1) {
      float om1 = __shfl_xor(m1, off, 64);
      float om2 = __shfl_xor(m2, off, 64);
      int   oc1 = __shfl_xor(c1, off, 64);
      bool take = (om1 > m1) || (om1 == m1 && oc1 < c1);
      m2 = __builtin_amdgcn_fmed3f(m1, om1, fmaxf(m2, om2));
      m1 = take ? om1 : m1;
      c1 = take ? oc1 : c1;
    }
    m1a[q] = m1; m2a[q] = m2; c1a[q] = c1;
  }

  if (col == 0) {
#pragma unroll
    for (int q = 0; q < 16; ++q) {
      int row = (q >> 2) * 16 + kq * 4 + (q & 3);
      redm[cg * 64 + row] = make_float2(m1a[q], m2a[q]);
      redi[cg * 64 + row] = c1a[q];
    }
  }
  if (cg == 0 && kq == 0) {
#pragma unroll
    for (int g = 0; g < 4; ++g) z2l[g * 16 + col] = z2p[g];
  }
  __syncthreads();

  if (tid < 64) {
    int row = tid;
    float M1 = -3.4e38f, M2 = -3.4e38f; int C1 = 0x7fffffff;
#pragma unroll
    for (int e = 0; e < 4; ++e) {
      float2 v = redm[e * 64 + row];
      int    ci = redi[e * 64 + row];
      bool take = (v.x > M1) || (v.x == M1 && ci < C1);
      M2 = __builtin_amdgcn_fmed3f(M1, v.x, fmaxf(M2, v.y));
      M1 = take ? v.x : M1;
      C1 = take ? ci : C1;
    }
    int grow = blockIdx.x * 64 + row;
    bool flg = (M1 - M2) < TAU_M;          // uncertified -> fp64 fixup
    win[row] = flg ? -1 : C1;
    if (!flg) {
      atomicAdd(&WS_COUNTS(ws)[C1], 1);
    } else {
      unsigned p = atomicAdd(WS_NFLAG(ws), 1u);
      WS_LIST(ws)[p] = (ushort)grow;
    }
    // ||z-e||^2 = ||z||^2 + 64 - 2*m1  (m1 err ~5e-4 -> loss err ~1e-6)
    float ssep = flg ? 0.f : (z2l[row] + 64.0f - 2.0f * M1);
#pragma unroll
    for (int off = 32; off; off >>= 1) ssep += __shfl_down(ssep, off, 64);
    if (tid == 0) atomicAdd(WS_SSE(ws), ssep);
  }
  __syncthreads();

  // quantized_st == emb[winner] in value: write gather directly, no z re-read
  {
    int row = tid >> 2, qtr = tid & 3;
    int wv = win[row];
    if (wv >= 0) {
      size_t grow = (size_t)blockIdx.x * 64 + row;
      const float4* ep = (const float4*)(emb + (size_t)wv * DIM) + qtr * 4;
      float4* op = (float4*)(outp + grow * DIM) + qtr * 4;
      op[0] = ep[0]; op[1] = ep[1]; op[2] = ep[2]; op[3] = ep[3];
    }
  }
}

// --------------------------------------------------------------- fixup ----
// fp64 full re-score of flagged rows from the compacted list (load-balanced
// grid-stride); writes their out rows, counts, sse.
__global__ __launch_bounds__(256) void vq_fixup(const float* __restrict__ z,
                                                const float* __restrict__ emb,
                                                void* ws,
                                                float* __restrict__ out) {
  int tid = threadIdx.x;
  __shared__ __align__(16) float zrow[DIM];
  __shared__ double rd[256];
  __shared__ int    ri[256];

  const int n = (int)*WS_NFLAG(ws);

  for (int i = blockIdx.x; i < n; i += 1024) {
    int row = (int)WS_LIST(ws)[i];
    if (tid < 16) *(float4*)&zrow[tid * 4] = ((const float4*)(z + (size_t)row * DIM))[tid];
    __syncthreads();

    double bd = 1e300; int bi = 0x7fffffff;
    for (int c = tid; c < KCODE; c += 256) {
      const float4* e4 = (const float4*)(emb + (size_t)c * DIM);
      double dot = 0.0, e2 = 0.0;
#pragma unroll
      for (int t = 0; t < 16; ++t) {
        float4 v = e4[t];
        float4 zz = *(const float4*)&zrow[t * 4];
        dot = fma((double)zz.x, (double)v.x, dot);
        dot = fma((double)zz.y, (double)v.y, dot);
        dot = fma((double)zz.z, (double)v.z, dot);
        dot = fma((double)zz.w, (double)v.w, dot);
        e2  = fma((double)v.x, (double)v.x, e2);
        e2  = fma((double)v.y, (double)v.y, e2);
        e2  = fma((double)v.z, (double)v.z, e2);
        e2  = fma((double)v.w, (double)v.w, e2);
      }
      double dist = e2 - 2.0 * dot;
      if (dist < bd || (dist == bd && c < bi)) { bd = dist; bi = c; }
    }
    rd[tid] = bd; ri[tid] = bi;
    __syncthreads();
    for (int st = 128; st; st >>= 1) {
      if (tid < st) {
        double od = rd[tid + st]; int oi = ri[tid + st];
        if (od < rd[tid] || (od == rd[tid] && oi < ri[tid])) { rd[tid] = od; ri[tid] = oi; }
      }
      __syncthreads();
    }
    int wi = ri[0];
    if (tid < 16) {
      float4 e  = ((const float4*)(emb + (size_t)wi * DIM))[tid];
      float4 zz = *(const float4*)&zrow[tid * 4];
      float4 qv;
      qv.x = zz.x + (e.x - zz.x); qv.y = zz.y + (e.y - zz.y);
      qv.z = zz.z + (e.z - zz.z); qv.w = zz.w + (e.w - zz.w);
      ((float4*)(out + (size_t)row * DIM))[tid] = qv;
      float dx = zz.x - e.x, dy = zz.y - e.y, dz = zz.z - e.z, dw = zz.w - e.w;
      float part = dx * dx + dy * dy + dz * dz + dw * dw;
      part += __shfl_down(part, 8, 64);
      part += __shfl_down(part, 4, 64);
      part += __shfl_down(part, 2, 64);
      part += __shfl_down(part, 1, 64);
      if (tid == 0) {
        atomicAdd(WS_SSE(ws), part);
        atomicAdd(&WS_COUNTS(ws)[wi], 1);
      }
    }
    __syncthreads();
  }
}

// ------------------------------------------------------------ finalize ----
__global__ __launch_bounds__(256) void vq_finalize(void* ws, float* __restrict__ out) {
  int tid = threadIdx.x;
  __shared__ float w4[4];
  float part = 0.f;
  for (int c = tid; c < KCODE; c += 256) {
    float p = (float)WS_COUNTS(ws)[c] * (1.0f / (float)NROWS);
    part += p * logf(p + 1e-10f);
  }
  for (int off = 32; off; off >>= 1) part += __shfl_down(part, off, 64);
  if ((tid & 63) == 0) w4[tid >> 6] = part;
  __syncthreads();
  if (tid == 0) {
    float ent = (w4[0] + w4[1]) + (w4[2] + w4[3]);
    float perp = expf(-ent);
    perp = fminf(perp, (float)KCODE);
    if (!isfinite(perp)) perp = 0.f;
    out[(size_t)NROWS * DIM]     = 0.25f * (*WS_SSE(ws)) / (float)((size_t)NROWS * DIM);
    out[(size_t)NROWS * DIM + 1] = perp;
  }
}

extern "C" void kernel_launch(void* const* d_in, const int* in_sizes, int n_in,
                              void* d_out, int out_size, void* d_ws, size_t ws_size,
                              hipStream_t stream) {
  const float* z   = (const float*)d_in[0];
  const float* emb = (const float*)d_in[1];
  float* out = (float*)d_out;
  (void)in_sizes; (void)n_in; (void)out_size; (void)ws_size;

  vq_init    <<<64,   256, 0, stream>>>(emb, d_ws);
  vq_main    <<<NROWS / 64, 256, 0, stream>>>(z, emb, d_ws, out);
  vq_fixup   <<<1024, 256, 0, stream>>>(z, emb, d_ws, out);
  vq_finalize<<<1,    256, 0, stream>>>(d_ws, out);
}